// Round 1
// baseline (107.275 us; speedup 1.0000x reference)
//
#include <hip/hip_runtime.h>

#define HH 768
#define WW 768
#define BC 4
#define NPIX (BC * HH * WW)

__global__ __launch_bounds__(256) void conv_thresh_kernel(
    const float* __restrict__ bev_map,
    const float* __restrict__ bev_scale,
    float* __restrict__ out)  // out[0:N]=conv, out[N:2N]=mask
{
    const int x = blockIdx.x * 256 + threadIdx.x;   // 768 = 3*256, always in range
    const int y = blockIdx.y;
    const int b = blockIdx.z;

    const size_t plane = (size_t)b * HH * WW;
    const float* __restrict__ m = bev_map + plane;

    // Load 5x5 neighborhood with zero padding, ReLU applied.
    float v[5][5];
#pragma unroll
    for (int dy = -2; dy <= 2; ++dy) {
        const int yy = y + dy;
        const bool yok = (unsigned)yy < (unsigned)HH;
#pragma unroll
        for (int dx = -2; dx <= 2; ++dx) {
            const int xx = x + dx;
            const bool ok = yok && ((unsigned)xx < (unsigned)WW);
            const float t = ok ? m[yy * WW + xx] : 0.0f;
            v[dy + 2][dx + 2] = fmaxf(t, 0.0f);
        }
    }

    // Ring sums by r^2 = dy^2+dx^2 in {0,1,2,4,5,8}
    const float c0 = v[2][2];
    const float s1 = v[1][2] + v[3][2] + v[2][1] + v[2][3];
    const float s2 = v[1][1] + v[1][3] + v[3][1] + v[3][3];
    const float s4 = v[0][2] + v[4][2] + v[2][0] + v[2][4];
    const float s5 = v[0][1] + v[0][3] + v[4][1] + v[4][3]
                   + v[1][0] + v[1][4] + v[3][0] + v[3][4];
    const float s8 = v[0][0] + v[0][4] + v[4][0] + v[4][4];

    const size_t idx = plane + (size_t)y * WW + x;
    const float sc = bev_scale[idx];
    const float t1 = -1.0f / (2.0f * sc * sc + 1e-6f);
    const float e1 = __expf(t1);      // w(r2) = e1^r2
    const float e2 = e1 * e1;
    const float e4 = e2 * e2;
    const float e5 = e4 * e1;
    const float e8 = e4 * e4;

    float conv = c0;
    conv = fmaf(e1, s1, conv);
    conv = fmaf(e2, s2, conv);
    conv = fmaf(e4, s4, conv);
    conv = fmaf(e5, s5, conv);
    conv = fmaf(e8, s8, conv);

    out[idx] = conv;
    out[idx + (size_t)NPIX] = (conv >= 0.5f) ? 1.0f : 0.0f;
}

extern "C" void kernel_launch(void* const* d_in, const int* in_sizes, int n_in,
                              void* d_out, int out_size, void* d_ws, size_t ws_size,
                              hipStream_t stream) {
    const float* bev_map   = (const float*)d_in[0];
    const float* bev_scale = (const float*)d_in[1];
    float* out = (float*)d_out;

    dim3 block(256, 1, 1);
    dim3 grid(WW / 256, HH, BC);
    conv_thresh_kernel<<<grid, block, 0, stream>>>(bev_map, bev_scale, out);
}

// Round 2
// 77.693 us; speedup vs baseline: 1.3808x; 1.3808x over previous
//
#include <hip/hip_runtime.h>

#define HH 768
#define WW 768
#define BC 4
#define NPIX (BC * HH * WW)

// 8 outputs/thread: 4 along x (float4-aligned), 2 along y (row reuse).
// Window per thread: 6 rows x 8 cols (x0-2 .. x0+5), loaded as float2|float4|float2.
__global__ __launch_bounds__(256) void conv_thresh_kernel(
    const float* __restrict__ bev_map,
    const float* __restrict__ bev_scale,
    float* __restrict__ out)  // out[0:N]=conv, out[N:2N]=mask
{
    const int tx = threadIdx.x;                      // 0..63
    const int ty = threadIdx.y;                      // 0..3
    const int x0 = (blockIdx.x * 64 + tx) * 4;       // output col base, multiple of 4
    const int y0 = blockIdx.y * 8 + ty * 2;          // output row base, 2 rows/thread
    const int b  = blockIdx.z;

    const size_t plane = (size_t)b * (HH * WW);
    const float* __restrict__ m = bev_map + plane;

    const bool leftok  = (x0 != 0);
    const bool rightok = (x0 != WW - 4);

    // Horizontal partial sums per row r and output column j (x = x0+j):
    //   h0 = w[x], h1 = w[x-1]+w[x+1], h2 = w[x-2]+w[x+2]   (w = relu(map))
    float h0[6][4], h1[6][4], h2[6][4];

#pragma unroll
    for (int r = 0; r < 6; ++r) {
        const int yy = y0 - 2 + r;
        const bool yok = (unsigned)yy < (unsigned)HH;   // wave-uniform (ty fixed per wave)
        const float* rowp = m + yy * WW + x0;
        float w[8];                                     // w[i] = relu(map[yy][x0-2+i])
        if (yok) {
            float4 t = *(const float4*)rowp;
            w[2] = fmaxf(t.x, 0.f); w[3] = fmaxf(t.y, 0.f);
            w[4] = fmaxf(t.z, 0.f); w[5] = fmaxf(t.w, 0.f);
            if (leftok) {
                float2 t2 = *(const float2*)(rowp - 2);
                w[0] = fmaxf(t2.x, 0.f); w[1] = fmaxf(t2.y, 0.f);
            } else { w[0] = 0.f; w[1] = 0.f; }
            if (rightok) {
                float2 t2 = *(const float2*)(rowp + 4);
                w[6] = fmaxf(t2.x, 0.f); w[7] = fmaxf(t2.y, 0.f);
            } else { w[6] = 0.f; w[7] = 0.f; }
        } else {
#pragma unroll
            for (int i = 0; i < 8; ++i) w[i] = 0.f;
        }
#pragma unroll
        for (int j = 0; j < 4; ++j) {
            h0[r][j] = w[j + 2];
            h1[r][j] = w[j + 1] + w[j + 3];
            h2[r][j] = w[j]     + w[j + 4];
        }
    }

#pragma unroll
    for (int k = 0; k < 2; ++k) {
        const int oy = y0 + k;
        const size_t idx = plane + (size_t)oy * WW + x0;
        const float4 scv = *(const float4*)(bev_scale + idx);
        float conv[4], mask[4];
#pragma unroll
        for (int j = 0; j < 4; ++j) {
            // Ring sums by r^2 from horizontal partials (rows k..k+4)
            const float c0 = h0[k + 2][j];
            const float s1 = h1[k + 2][j] + h0[k + 1][j] + h0[k + 3][j];
            const float s2 = h1[k + 1][j] + h1[k + 3][j];
            const float s4 = h2[k + 2][j] + h0[k][j]     + h0[k + 4][j];
            const float s5 = h2[k + 1][j] + h2[k + 3][j] + h1[k][j] + h1[k + 4][j];
            const float s8 = h2[k][j]     + h2[k + 4][j];

            const float sc = (j == 0) ? scv.x : (j == 1) ? scv.y : (j == 2) ? scv.z : scv.w;
            const float t1 = -1.0f / (2.0f * sc * sc + 1e-6f);
            const float e1 = __expf(t1);      // w(r2) = e1^r2
            const float e2 = e1 * e1;
            const float e4 = e2 * e2;
            const float e5 = e4 * e1;
            const float e8 = e4 * e4;

            float cv = c0;
            cv = fmaf(e1, s1, cv);
            cv = fmaf(e2, s2, cv);
            cv = fmaf(e4, s4, cv);
            cv = fmaf(e5, s5, cv);
            cv = fmaf(e8, s8, cv);
            conv[j] = cv;
            mask[j] = (cv >= 0.5f) ? 1.0f : 0.0f;
        }
        *(float4*)(out + idx)        = make_float4(conv[0], conv[1], conv[2], conv[3]);
        *(float4*)(out + idx + (size_t)NPIX) = make_float4(mask[0], mask[1], mask[2], mask[3]);
    }
}

extern "C" void kernel_launch(void* const* d_in, const int* in_sizes, int n_in,
                              void* d_out, int out_size, void* d_ws, size_t ws_size,
                              hipStream_t stream) {
    const float* bev_map   = (const float*)d_in[0];
    const float* bev_scale = (const float*)d_in[1];
    float* out = (float*)d_out;

    dim3 block(64, 4, 1);
    dim3 grid(WW / 256, HH / 8, BC);   // (3, 96, 4) = 1152 blocks, 4 waves each
    conv_thresh_kernel<<<grid, block, 0, stream>>>(bev_map, bev_scale, out);
}